// Round 4
// baseline (7290.945 us; speedup 1.0000x reference)
//
#include <hip/hip_runtime.h>
#include <hip/hip_bf16.h>

typedef __bf16 bf16x8 __attribute__((ext_vector_type(8)));
typedef float f32x4 __attribute__((ext_vector_type(4)));

constexpr int Bb = 128, Tt = 512, Ff = 64, Hh = 512, Gg = 2048;
constexpr int K0 = Hh + Ff;   // 576  = [h | x]
constexpr int K1 = Hh + Hh;   // 1024 = [h1 | h0]

// workspace byte offsets (16B-aligned).
// Weights: single bf16 (fixed perturbation ~2^-9, systematic out-error ~1e-4).
// h-state: hi+lo split bf16 (~17 mantissa bits) — recurrent error random-walks, needs it.
constexpr size_t OFF_W0  = 0;                                  // bf16 [2048][576]  [w_hh_0 | w_ih_0]
constexpr size_t OFF_W1  = OFF_W0 + (size_t)Gg * K0 * 2;       // bf16 [2048][1024] [w_hh_1 | w_ih_1]
constexpr size_t OFF_B0  = OFF_W1 + (size_t)Gg * K1 * 2;       // f32 [2048]
constexpr size_t OFF_B1  = OFF_B0 + (size_t)Gg * 4;
constexpr size_t OFF_H0H = OFF_B1 + (size_t)Gg * 4;            // bf16 [2][128][512] (dbuf parity)
constexpr size_t OFF_H0L = OFF_H0H + (size_t)2 * Bb * Hh * 2;
constexpr size_t OFF_H1H = OFF_H0L + (size_t)2 * Bb * Hh * 2;
constexpr size_t OFF_H1L = OFF_H1H + (size_t)2 * Bb * Hh * 2;
constexpr size_t OFF_HF  = OFF_H1L + (size_t)2 * Bb * Hh * 2;  // f32 [128][512] final h1
constexpr size_t OFF_FLG = OFF_HF + (size_t)Bb * Hh * 4;       // u32 [8][16] group barrier ctrs
// total ~7.9 MiB

__global__ void prep(const float* __restrict__ wih0, const float* __restrict__ whh0,
                     const float* __restrict__ bih0, const float* __restrict__ bhh0,
                     const float* __restrict__ wih1, const float* __restrict__ whh1,
                     const float* __restrict__ bih1, const float* __restrict__ bhh1,
                     unsigned char* __restrict__ ws)
{
  __hip_bfloat16* W0 = reinterpret_cast<__hip_bfloat16*>(ws + OFF_W0);
  __hip_bfloat16* W1 = reinterpret_cast<__hip_bfloat16*>(ws + OFF_W1);
  float* B0 = reinterpret_cast<float*>(ws + OFF_B0);
  float* B1 = reinterpret_cast<float*>(ws + OFF_B1);
  __hip_bfloat16* H0H = reinterpret_cast<__hip_bfloat16*>(ws + OFF_H0H);
  __hip_bfloat16* H0L = reinterpret_cast<__hip_bfloat16*>(ws + OFF_H0L);
  __hip_bfloat16* H1H = reinterpret_cast<__hip_bfloat16*>(ws + OFF_H1H);
  __hip_bfloat16* H1L = reinterpret_cast<__hip_bfloat16*>(ws + OFF_H1L);
  unsigned int* FLG = reinterpret_cast<unsigned int*>(ws + OFF_FLG);

  const size_t tid = (size_t)blockIdx.x * blockDim.x + threadIdx.x;
  const size_t stp = (size_t)gridDim.x * blockDim.x;

  // layer-0 weights packed [w_hh_0 | w_ih_0]
  for (size_t i = tid; i < (size_t)Gg * K0; i += stp) {
    int g = (int)(i / K0), k = (int)(i % K0);
    float v = (k < Hh) ? whh0[(size_t)g * Hh + k] : wih0[(size_t)g * Ff + (k - Hh)];
    W0[i] = __float2bfloat16(v);
  }
  // layer-1 weights packed [w_hh_1 | w_ih_1]
  for (size_t i = tid; i < (size_t)Gg * K1; i += stp) {
    int g = (int)(i / K1), k = (int)(i % K1);
    float v = (k < Hh) ? whh1[(size_t)g * Hh + k] : wih1[(size_t)g * Hh + (k - Hh)];
    W1[i] = __float2bfloat16(v);
  }
  for (size_t i = tid; i < (size_t)Gg; i += stp) {
    B0[i] = bih0[i] + bhh0[i];
    B1[i] = bih1[i] + bhh1[i];
  }
  // zero h buffers (both parities, hi+lo) and barrier flags (ws poisoned 0xAA pre-launch)
  for (size_t i = tid; i < (size_t)2 * Bb * Hh; i += stp) {
    __hip_bfloat16 z = __float2bfloat16(0.f);
    H0H[i] = z; H0L[i] = z; H1H[i] = z; H1L[i] = z;
  }
  for (size_t i = tid; i < 128; i += stp) FLG[i] = 0u;
}

__device__ __forceinline__ float sigf(float x)   { return 1.f / (1.f + __expf(-x)); }
__device__ __forceinline__ float tanhf_(float x) { return 1.f - 2.f / (1.f + __expf(2.f * x)); }

// Single-phase barrier across the 32 WGs of one batch-group (monotonic counter,
// no reset; target = 32*(it+1)). Agent scope: release publishes the block's h
// stores (ordered via __syncthreads), acquire makes them visible to waiters.
__device__ __forceinline__ void group_barrier(unsigned int* flag, unsigned int target) {
  __syncthreads();
  if (threadIdx.x == 0) {
    __hip_atomic_fetch_add(flag, 1u, __ATOMIC_ACQ_REL, __HIP_MEMORY_SCOPE_AGENT);
    while (__hip_atomic_load(flag, __ATOMIC_ACQUIRE, __HIP_MEMORY_SCOPE_AGENT) < target)
      __builtin_amdgcn_s_sleep(1);
  }
  __syncthreads();
}

// PLAIN launch (no cooperative API — it was silently failing and is not needed:
// barriers are per-group atomics). 256 WGs x 256 threads; >256 VGPR => exactly
// 1 WG/CU => grid 256 == CU count => all blocks co-resident by construction.
// WG = (batch-group gb: 16 rows) x (hidden slice hs: 16 units); 4 waves K-split.
// Weights single-bf16 register-resident (208 VGPR); h/x hi+lo => 2 MFMAs/slice.
__global__ __launch_bounds__(256, 1)
void lstm_main(unsigned char* __restrict__ ws,
               const float* __restrict__ xg,
               const float* __restrict__ linw, const float* __restrict__ linb,
               float* __restrict__ out)
{
  const __hip_bfloat16* W0 = reinterpret_cast<const __hip_bfloat16*>(ws + OFF_W0);
  const __hip_bfloat16* W1 = reinterpret_cast<const __hip_bfloat16*>(ws + OFF_W1);
  const float* B0 = reinterpret_cast<const float*>(ws + OFF_B0);
  const float* B1 = reinterpret_cast<const float*>(ws + OFF_B1);
  __hip_bfloat16* H0H = reinterpret_cast<__hip_bfloat16*>(ws + OFF_H0H);
  __hip_bfloat16* H0L = reinterpret_cast<__hip_bfloat16*>(ws + OFF_H0L);
  __hip_bfloat16* H1H = reinterpret_cast<__hip_bfloat16*>(ws + OFF_H1H);
  __hip_bfloat16* H1L = reinterpret_cast<__hip_bfloat16*>(ws + OFF_H1L);
  float* HF = reinterpret_cast<float*>(ws + OFF_HF);
  unsigned int* FLG = reinterpret_cast<unsigned int*>(ws + OFF_FLG);

  const int tid  = threadIdx.x;
  const int lane = tid & 63;
  const int w4   = tid >> 6;          // wave id 0..3 (K-split)
  const int gb   = blockIdx.x & 7;    // batch group (XCD-local under round-robin dispatch)
  const int hs   = blockIdx.x >> 3;   // hidden slice 0..31
  const int b0   = gb << 4;
  const int j0   = hs << 4;
  const int fr   = lane & 15;         // frag row (A batch-row / B gate-row)
  const int fk   = (lane >> 4) << 3;  // frag k offset within 32-k slice
  unsigned int* gflag = FLG + gb * 16;

  // partial sums: [wave][gate][unit j][pitch-20 batch m] -> b128 writes, ~2-way conflicts (free)
  __shared__ float p0[4][4][16][20];
  __shared__ float p1[4][4][16][20];

  // layer-0 K split: 18 slices of 32 over 4 waves = {5,5,4,4}
  const int ks0 = (w4 < 2) ? w4 * 5 : 10 + (w4 - 2) * 4;
  const int kc0 = (w4 < 2) ? 5 : 4;

  // --- register-resident weight fragments (single bf16) ---
  bf16x8 wf0[4][5], wf1[4][8];
  #pragma unroll
  for (int g = 0; g < 4; ++g) {
    const size_t rw0 = (size_t)(g * Hh + j0 + fr) * K0;
    const size_t rw1 = (size_t)(g * Hh + j0 + fr) * K1;
    #pragma unroll
    for (int s = 0; s < 5; ++s) {
      int ks = ks0 + ((s < kc0) ? s : 0);   // clamp: unused slot replicates
      wf0[g][s] = *reinterpret_cast<const bf16x8*>(W0 + rw0 + ks * 32 + fk);
    }
    #pragma unroll
    for (int s = 0; s < 8; ++s)
      wf1[g][s] = *reinterpret_cast<const bf16x8*>(W1 + rw1 + (w4 * 8 + s) * 32 + fk);
  }

  // update-phase mapping: thread <-> (m = batch row-in-group, j = unit-in-slice)
  const int um = tid >> 4, uj = tid & 15;
  float bs0[4], bs1[4];
  #pragma unroll
  for (int g = 0; g < 4; ++g) {
    bs0[g] = B0[g * Hh + j0 + uj];
    bs1[g] = B1[g * Hh + j0 + uj];
  }
  float c0 = 0.f, c1 = 0.f;   // cell state fp32 in registers for the whole sequence

  // iteration it: layer0 computes t=it (it<512); layer1 computes t'=it-1 (it>=1)
  for (int it = 0; it <= Tt; ++it) {
    const int p = it & 1;
    const size_t rdo = (size_t)p * (Bb * Hh), wro = (size_t)(p ^ 1) * (Bb * Hh);
    const __hip_bfloat16 *h0rH = H0H + rdo, *h0rL = H0L + rdo;
    const __hip_bfloat16 *h1rH = H1H + rdo, *h1rL = H1L + rdo;

    // ---- layer 0: gates(t=it) = W0 * [h0 | x_t]  (A = hi+lo -> 2 MFMAs/slice) ----
    if (it < Tt) {
      bf16x8 ah[5], al[5];
      #pragma unroll
      for (int s = 0; s < 5; ++s) {
        const int k0 = (ks0 + ((s < kc0) ? s : 0)) * 32;
        if (k0 < Hh) {                       // wave/slot-uniform branch
          const size_t off = (size_t)(b0 + fr) * Hh + k0 + fk;
          ah[s] = *reinterpret_cast<const bf16x8*>(h0rH + off);
          al[s] = *reinterpret_cast<const bf16x8*>(h0rL + off);
        } else {                             // x part: split fp32 -> hi/lo in-register
          const float* xs = xg + ((size_t)(b0 + fr) * Tt + it) * Ff + (k0 - Hh) + fk;
          f32x4 v0 = *reinterpret_cast<const f32x4*>(xs);
          f32x4 v1 = *reinterpret_cast<const f32x4*>(xs + 4);
          bf16x8 hh, ll;
          #pragma unroll
          for (int j = 0; j < 4; ++j) {
            float v = v0[j];  __bf16 hb = (__bf16)v;
            hh[j] = hb;  ll[j] = (__bf16)(v - (float)hb);
            v = v1[j];  hb = (__bf16)v;
            hh[j + 4] = hb;  ll[j + 4] = (__bf16)(v - (float)hb);
          }
          ah[s] = hh;  al[s] = ll;
        }
      }
      f32x4 acc[4] = {};
      #pragma unroll
      for (int s = 0; s < 5; ++s) {
        if (s < kc0) {                       // wave-uniform
          #pragma unroll
          for (int g = 0; g < 4; ++g) {
            acc[g] = __builtin_amdgcn_mfma_f32_16x16x32_bf16(ah[s], wf0[g][s], acc[g], 0, 0, 0);
            acc[g] = __builtin_amdgcn_mfma_f32_16x16x32_bf16(al[s], wf0[g][s], acc[g], 0, 0, 0);
          }
        }
      }
      #pragma unroll
      for (int g = 0; g < 4; ++g)   // C/D: col(j)=lane&15, row(m)=4*(lane>>4)+r
        *reinterpret_cast<f32x4*>(&p0[w4][g][fr][(lane >> 4) << 2]) = acc[g];
    }

    // ---- layer 1: gates(t'=it-1) = W1 * [h1 | h0_new]  (2 chunks of 4 slices) ----
    if (it >= 1) {
      f32x4 acc[4] = {};
      #pragma unroll
      for (int c = 0; c < 2; ++c) {
        bf16x8 ah[4], al[4];
        #pragma unroll
        for (int s = 0; s < 4; ++s) {
          const int k0 = (w4 * 8 + c * 4 + s) * 32;
          const size_t roff = (size_t)(b0 + fr) * Hh;
          const __hip_bfloat16* sH = (k0 < Hh) ? (h1rH + roff + k0 + fk) : (h0rH + roff + (k0 - Hh) + fk);
          const __hip_bfloat16* sL = (k0 < Hh) ? (h1rL + roff + k0 + fk) : (h0rL + roff + (k0 - Hh) + fk);
          ah[s] = *reinterpret_cast<const bf16x8*>(sH);
          al[s] = *reinterpret_cast<const bf16x8*>(sL);
        }
        #pragma unroll
        for (int s = 0; s < 4; ++s) {
          #pragma unroll
          for (int g = 0; g < 4; ++g) {
            acc[g] = __builtin_amdgcn_mfma_f32_16x16x32_bf16(ah[s], wf1[g][c * 4 + s], acc[g], 0, 0, 0);
            acc[g] = __builtin_amdgcn_mfma_f32_16x16x32_bf16(al[s], wf1[g][c * 4 + s], acc[g], 0, 0, 0);
          }
        }
      }
      #pragma unroll
      for (int g = 0; g < 4; ++g)
        *reinterpret_cast<f32x4*>(&p1[w4][g][fr][(lane >> 4) << 2]) = acc[g];
    }
    __syncthreads();

    // ---- cross-wave reduce + gates + state update + h publish (hi/lo) ----
    if (it < Tt) {
      float gv[4];
      #pragma unroll
      for (int g = 0; g < 4; ++g)
        gv[g] = p0[0][g][uj][um] + p0[1][g][uj][um] + p0[2][g][uj][um] + p0[3][g][uj][um] + bs0[g];
      float iv = sigf(gv[0]), fv = sigf(gv[1]), gg = tanhf_(gv[2]), ov = sigf(gv[3]);
      c0 = fv * c0 + iv * gg;
      float hv = ov * tanhf_(c0);
      const size_t off = wro + (size_t)(b0 + um) * Hh + j0 + uj;
      __hip_bfloat16 hb = __float2bfloat16(hv);
      H0H[off] = hb;
      H0L[off] = __float2bfloat16(hv - __bfloat162float(hb));
    }
    if (it >= 1) {
      float gv[4];
      #pragma unroll
      for (int g = 0; g < 4; ++g)
        gv[g] = p1[0][g][uj][um] + p1[1][g][uj][um] + p1[2][g][uj][um] + p1[3][g][uj][um] + bs1[g];
      float iv = sigf(gv[0]), fv = sigf(gv[1]), gg = tanhf_(gv[2]), ov = sigf(gv[3]);
      c1 = fv * c1 + iv * gg;
      float hv = ov * tanhf_(c1);
      const size_t off = wro + (size_t)(b0 + um) * Hh + j0 + uj;
      __hip_bfloat16 hb = __float2bfloat16(hv);
      H1H[off] = hb;
      H1L[off] = __float2bfloat16(hv - __bfloat162float(hb));
      if (it == Tt) HF[(size_t)(b0 + um) * Hh + j0 + uj] = hv;   // fp32 stash
    }

    group_barrier(gflag, 32u * (unsigned)(it + 1));
  }

  // ---- epilogue (in-group): block (gb, hs<16) -> out[gb*16 + hs], fp32 exact ----
  if (hs < 16 && tid < 64) {
    const int b = (gb << 4) + hs;
    float s = 0.f;
    #pragma unroll
    for (int i = 0; i < 8; ++i) {
      int j = i * 64 + tid;
      s += HF[(size_t)b * Hh + j] * linw[j];
    }
    #pragma unroll
    for (int off = 32; off >= 1; off >>= 1) s += __shfl_down(s, off, 64);
    if (tid == 0) out[b] = s + linb[0];
  }
}

extern "C" void kernel_launch(void* const* d_in, const int* in_sizes, int n_in,
                              void* d_out, int out_size, void* d_ws, size_t ws_size,
                              hipStream_t stream)
{
  const float* x    = (const float*)d_in[0];
  const float* wih0 = (const float*)d_in[1];
  const float* whh0 = (const float*)d_in[2];
  const float* bih0 = (const float*)d_in[3];
  const float* bhh0 = (const float*)d_in[4];
  const float* wih1 = (const float*)d_in[5];
  const float* whh1 = (const float*)d_in[6];
  const float* bih1 = (const float*)d_in[7];
  const float* bhh1 = (const float*)d_in[8];
  const float* linw = (const float*)d_in[9];
  const float* linb = (const float*)d_in[10];
  float* outp = (float*)d_out;
  unsigned char* ws = (unsigned char*)d_ws;

  prep<<<256, 256, 0, stream>>>(wih0, whh0, bih0, bhh0, wih1, whh1, bih1, bhh1, ws);
  lstm_main<<<256, 256, 0, stream>>>(ws, x, linw, linb, outp);
}

// Round 5
// 4503.763 us; speedup vs baseline: 1.6189x; 1.6189x over previous
//
#include <hip/hip_runtime.h>
#include <hip/hip_bf16.h>

typedef __bf16 bf16x8 __attribute__((ext_vector_type(8)));
typedef float f32x4 __attribute__((ext_vector_type(4)));
typedef unsigned uint4v __attribute__((ext_vector_type(4)));
typedef unsigned long long u64;

constexpr int Bb = 128, Tt = 512, Ff = 64, Hh = 512, Gg = 2048;
constexpr int K0 = Hh + Ff;   // 576  = [h | x]
constexpr int K1 = Hh + Hh;   // 1024 = [h1 | h0]
constexpr int NITER = Tt + 1; // 513

// ws offsets (16B-aligned). h planes store PACKED u32 = bf16_hi | bf16_lo<<16
// (value = hi + lo, ~17 mantissa bits; exchanged via system-scope (IF$) ops).
constexpr size_t OFF_W0  = 0;                                   // bf16 [2048][576]  [w_hh_0 | w_ih_0]
constexpr size_t OFF_W1  = OFF_W0 + (size_t)Gg * K0 * 2;        // bf16 [2048][1024] [w_hh_1 | w_ih_1]
constexpr size_t OFF_B0  = OFF_W1 + (size_t)Gg * K1 * 2;        // f32 [2048]
constexpr size_t OFF_B1  = OFF_B0 + (size_t)Gg * 4;
constexpr size_t OFF_HI0 = OFF_B1 + (size_t)Gg * 4;             // u32 [2][128][512] (dbuf parity)
constexpr size_t OFF_HI1 = OFF_HI0 + (size_t)2 * Bb * Hh * 4;   // u32 [2][128][512]
constexpr size_t OFF_HF  = OFF_HI1 + (size_t)2 * Bb * Hh * 4;   // f32 [128][512] final h1
constexpr size_t OFF_FLG = OFF_HF + (size_t)Bb * Hh * 4;        // u32 [513][8][32] flag-per-WG barrier
// total ~8.4 MiB

__global__ void prep(const float* __restrict__ wih0, const float* __restrict__ whh0,
                     const float* __restrict__ bih0, const float* __restrict__ bhh0,
                     const float* __restrict__ wih1, const float* __restrict__ whh1,
                     const float* __restrict__ bih1, const float* __restrict__ bhh1,
                     unsigned char* __restrict__ ws)
{
  __hip_bfloat16* W0 = reinterpret_cast<__hip_bfloat16*>(ws + OFF_W0);
  __hip_bfloat16* W1 = reinterpret_cast<__hip_bfloat16*>(ws + OFF_W1);
  float* B0 = reinterpret_cast<float*>(ws + OFF_B0);
  float* B1 = reinterpret_cast<float*>(ws + OFF_B1);
  unsigned* HI0 = reinterpret_cast<unsigned*>(ws + OFF_HI0);
  unsigned* HI1 = reinterpret_cast<unsigned*>(ws + OFF_HI1);
  unsigned* FLG = reinterpret_cast<unsigned*>(ws + OFF_FLG);

  const size_t tid = (size_t)blockIdx.x * blockDim.x + threadIdx.x;
  const size_t stp = (size_t)gridDim.x * blockDim.x;

  for (size_t i = tid; i < (size_t)Gg * K0; i += stp) {
    int g = (int)(i / K0), k = (int)(i % K0);
    float v = (k < Hh) ? whh0[(size_t)g * Hh + k] : wih0[(size_t)g * Ff + (k - Hh)];
    W0[i] = __float2bfloat16(v);
  }
  for (size_t i = tid; i < (size_t)Gg * K1; i += stp) {
    int g = (int)(i / K1), k = (int)(i % K1);
    float v = (k < Hh) ? whh1[(size_t)g * Hh + k] : wih1[(size_t)g * Hh + (k - Hh)];
    W1[i] = __float2bfloat16(v);
  }
  for (size_t i = tid; i < (size_t)Gg; i += stp) {
    B0[i] = bih0[i] + bhh0[i];
    B1[i] = bih1[i] + bhh1[i];
  }
  // zero h planes (both parities; packed 0 == (0,0)) and ALL barrier flags
  for (size_t i = tid; i < (size_t)2 * Bb * Hh; i += stp) { HI0[i] = 0u; HI1[i] = 0u; }
  for (size_t i = tid; i < (size_t)NITER * 256; i += stp) FLG[i] = 0u;
}

__device__ __forceinline__ float sigf(float x)   { return 1.f / (1.f + __expf(-x)); }
__device__ __forceinline__ float tanhf_(float x) { return 1.f - 2.f / (1.f + __expf(2.f * x)); }

// pack value as bf16 hi|lo<<16 (RNE both) — identical numerics to round-4 split
__device__ __forceinline__ unsigned pack_hl(float v) {
  __bf16 hb = (__bf16)v;
  __bf16 lb = (__bf16)(v - (float)hb);
  return (unsigned)__builtin_bit_cast(unsigned short, hb)
       | ((unsigned)__builtin_bit_cast(unsigned short, lb) << 16);
}

// load 8 packed h elements via system-scope (IF$-coherent) 8B atomics; unpack
// to hi/lo bf16x8 frags with v_perm (2 VALU per 2 elements, hidden under MFMA).
__device__ __forceinline__ void load_hl8(const unsigned* p, bf16x8& hi, bf16x8& lo) {
  u64 q0 = __hip_atomic_load((const u64*)(p + 0), __ATOMIC_RELAXED, __HIP_MEMORY_SCOPE_SYSTEM);
  u64 q1 = __hip_atomic_load((const u64*)(p + 2), __ATOMIC_RELAXED, __HIP_MEMORY_SCOPE_SYSTEM);
  u64 q2 = __hip_atomic_load((const u64*)(p + 4), __ATOMIC_RELAXED, __HIP_MEMORY_SCOPE_SYSTEM);
  u64 q3 = __hip_atomic_load((const u64*)(p + 6), __ATOMIC_RELAXED, __HIP_MEMORY_SCOPE_SYSTEM);
  unsigned a0 = (unsigned)q0, a1 = (unsigned)(q0 >> 32);
  unsigned a2 = (unsigned)q1, a3 = (unsigned)(q1 >> 32);
  unsigned a4 = (unsigned)q2, a5 = (unsigned)(q2 >> 32);
  unsigned a6 = (unsigned)q3, a7 = (unsigned)(q3 >> 32);
  uint4v hw = { __builtin_amdgcn_perm(a1, a0, 0x05040100u),
                __builtin_amdgcn_perm(a3, a2, 0x05040100u),
                __builtin_amdgcn_perm(a5, a4, 0x05040100u),
                __builtin_amdgcn_perm(a7, a6, 0x05040100u) };
  uint4v lw = { __builtin_amdgcn_perm(a1, a0, 0x07060302u),
                __builtin_amdgcn_perm(a3, a2, 0x07060302u),
                __builtin_amdgcn_perm(a5, a4, 0x07060302u),
                __builtin_amdgcn_perm(a7, a6, 0x07060302u) };
  hi = __builtin_bit_cast(bf16x8, hw);
  lo = __builtin_bit_cast(bf16x8, lw);
}

// Contention-free group barrier: each WG stores 1 to its OWN flag slot
// (relaxed system scope -> lands at IF$ after vmcnt(0) drained the h-stores);
// wave 0's 32 lanes poll the group's 32 slots in parallel (coalesced 128B).
// No RMW serialization, no acq/rel cache invalidation -> L2 stays warm.
__device__ __forceinline__ void group_barrier(unsigned* FLG, int it, int gb, int hs,
                                              int lane, int w4) {
  asm volatile("s_waitcnt vmcnt(0)" ::: "memory");  // each wave drains its h-stores
  __syncthreads();                                   // all waves drained
  unsigned* base = FLG + (size_t)it * 256 + gb * 32;
  if (threadIdx.x == 0)
    __hip_atomic_store(base + hs, 1u, __ATOMIC_RELAXED, __HIP_MEMORY_SCOPE_SYSTEM);
  if (w4 == 0 && lane < 32) {
    while (__hip_atomic_load(base + lane, __ATOMIC_RELAXED, __HIP_MEMORY_SCOPE_SYSTEM) == 0u) {}
  }
  asm volatile("" ::: "memory");
  __syncthreads();
}

// 256 WGs x 256 threads, 1 WG/CU (plain launch; no cooperative API).
// WG = (batch-group gb: 16 rows) x (hidden slice hs: 16 units); 4 waves K-split.
// Weights register-resident (208 VGPR, pinned via asm so they CANNOT be
// re-loaded per iteration — round-4's VGPR=164 showed the ws-aliasing demoted them).
__global__ __launch_bounds__(256, 1)
void lstm_main(const __hip_bfloat16* __restrict__ W0, const __hip_bfloat16* __restrict__ W1,
               const float* __restrict__ B0, const float* __restrict__ B1,
               unsigned* __restrict__ HI0, unsigned* __restrict__ HI1,
               float* __restrict__ HF, unsigned* __restrict__ FLG,
               const float* __restrict__ xg,
               const float* __restrict__ linw, const float* __restrict__ linb,
               float* __restrict__ out)
{
  const int tid  = threadIdx.x;
  const int lane = tid & 63;
  const int w4   = tid >> 6;          // wave id 0..3 (K-split)
  const int gb   = blockIdx.x & 7;    // batch group
  const int hs   = blockIdx.x >> 3;   // hidden slice 0..31
  const int b0   = gb << 4;
  const int j0   = hs << 4;
  const int fr   = lane & 15;         // frag row (A batch-row / B gate-row)
  const int fk   = (lane >> 4) << 3;  // frag k offset within 32-k slice

  // partial sums: [wave][gate][unit j][pitch-20 batch m] -> b128 writes, ~2-way conflicts (free)
  __shared__ float p0[4][4][16][20];
  __shared__ float p1[4][4][16][20];

  // layer-0 K split: 18 slices of 32 over 4 waves = {5,5,4,4}
  const int ks0 = (w4 < 2) ? w4 * 5 : 10 + (w4 - 2) * 4;
  const int kc0 = (w4 < 2) ? 5 : 4;

  // --- register-resident weight fragments (single bf16) ---
  bf16x8 wf0[4][5], wf1[4][8];
  #pragma unroll
  for (int g = 0; g < 4; ++g) {
    const size_t rw0 = (size_t)(g * Hh + j0 + fr) * K0;
    const size_t rw1 = (size_t)(g * Hh + j0 + fr) * K1;
    #pragma unroll
    for (int s = 0; s < 5; ++s) {
      int ks = ks0 + ((s < kc0) ? s : 0);   // clamp: unused slot replicates
      wf0[g][s] = *reinterpret_cast<const bf16x8*>(W0 + rw0 + ks * 32 + fk);
    }
    #pragma unroll
    for (int s = 0; s < 8; ++s)
      wf1[g][s] = *reinterpret_cast<const bf16x8*>(W1 + rw1 + (w4 * 8 + s) * 32 + fk);
  }
  // pin: asm makes values opaque -> compiler cannot rematerialize the loads
  #pragma unroll
  for (int g = 0; g < 4; ++g) {
    #pragma unroll
    for (int s = 0; s < 5; ++s) asm volatile("" : "+v"(wf0[g][s]));
    #pragma unroll
    for (int s = 0; s < 8; ++s) asm volatile("" : "+v"(wf1[g][s]));
  }

  // update-phase mapping: thread <-> (m = batch row-in-group, j = unit-in-slice)
  const int um = tid >> 4, uj = tid & 15;
  float bs0[4], bs1[4];
  #pragma unroll
  for (int g = 0; g < 4; ++g) {
    bs0[g] = B0[g * Hh + j0 + uj];
    bs1[g] = B1[g * Hh + j0 + uj];
  }
  float c0 = 0.f, c1 = 0.f;   // cell state fp32 in registers for the whole sequence

  // iteration it: layer0 computes t=it (it<512); layer1 computes t'=it-1 (it>=1)
  for (int it = 0; it <= Tt; ++it) {
    const int p = it & 1;
    const size_t rdo = (size_t)p * (Bb * Hh), wro = (size_t)(p ^ 1) * (Bb * Hh);
    const unsigned* h0r = HI0 + rdo;
    const unsigned* h1r = HI1 + rdo;

    // ---- layer 0: gates(t=it) = W0 * [h0 | x_t]  (A = hi+lo -> 2 MFMAs/slice) ----
    if (it < Tt) {
      bf16x8 ah[5], al[5];
      #pragma unroll
      for (int s = 0; s < 5; ++s) {
        const int k0 = (ks0 + ((s < kc0) ? s : 0)) * 32;
        if (k0 < Hh) {                       // wave/slot-uniform branch
          load_hl8(h0r + (size_t)(b0 + fr) * Hh + k0 + fk, ah[s], al[s]);
        } else {                             // x part: split fp32 -> hi/lo in-register
          const float* xs = xg + ((size_t)(b0 + fr) * Tt + it) * Ff + (k0 - Hh) + fk;
          f32x4 v0 = *reinterpret_cast<const f32x4*>(xs);
          f32x4 v1 = *reinterpret_cast<const f32x4*>(xs + 4);
          bf16x8 hh, ll;
          #pragma unroll
          for (int j = 0; j < 4; ++j) {
            float v = v0[j];  __bf16 hb = (__bf16)v;
            hh[j] = hb;  ll[j] = (__bf16)(v - (float)hb);
            v = v1[j];  hb = (__bf16)v;
            hh[j + 4] = hb;  ll[j + 4] = (__bf16)(v - (float)hb);
          }
          ah[s] = hh;  al[s] = ll;
        }
      }
      f32x4 acc[4] = {};
      #pragma unroll
      for (int s = 0; s < 5; ++s) {
        if (s < kc0) {                       // wave-uniform
          #pragma unroll
          for (int g = 0; g < 4; ++g) {
            acc[g] = __builtin_amdgcn_mfma_f32_16x16x32_bf16(ah[s], wf0[g][s], acc[g], 0, 0, 0);
            acc[g] = __builtin_amdgcn_mfma_f32_16x16x32_bf16(al[s], wf0[g][s], acc[g], 0, 0, 0);
          }
        }
      }
      #pragma unroll
      for (int g = 0; g < 4; ++g)   // C/D: col(j)=lane&15, row(m)=4*(lane>>4)+r
        *reinterpret_cast<f32x4*>(&p0[w4][g][fr][(lane >> 4) << 2]) = acc[g];
    }

    // ---- layer 1: gates(t'=it-1) = W1 * [h1 | h0_new]  (2 chunks of 4 slices) ----
    if (it >= 1) {
      f32x4 acc[4] = {};
      #pragma unroll
      for (int c = 0; c < 2; ++c) {
        bf16x8 ah[4], al[4];
        #pragma unroll
        for (int s = 0; s < 4; ++s) {
          const int k0 = (w4 * 8 + c * 4 + s) * 32;
          const size_t roff = (size_t)(b0 + fr) * Hh;
          const unsigned* src = (k0 < Hh) ? (h1r + roff + k0 + fk)
                                          : (h0r + roff + (k0 - Hh) + fk);
          load_hl8(src, ah[s], al[s]);
        }
        #pragma unroll
        for (int s = 0; s < 4; ++s) {
          #pragma unroll
          for (int g = 0; g < 4; ++g) {
            acc[g] = __builtin_amdgcn_mfma_f32_16x16x32_bf16(ah[s], wf1[g][c * 4 + s], acc[g], 0, 0, 0);
            acc[g] = __builtin_amdgcn_mfma_f32_16x16x32_bf16(al[s], wf1[g][c * 4 + s], acc[g], 0, 0, 0);
          }
        }
      }
      #pragma unroll
      for (int g = 0; g < 4; ++g)
        *reinterpret_cast<f32x4*>(&p1[w4][g][fr][(lane >> 4) << 2]) = acc[g];
    }
    __syncthreads();

    // ---- cross-wave reduce + gates + state update + h publish (packed, IF$) ----
    if (it < Tt) {
      float gv[4];
      #pragma unroll
      for (int g = 0; g < 4; ++g)
        gv[g] = p0[0][g][uj][um] + p0[1][g][uj][um] + p0[2][g][uj][um] + p0[3][g][uj][um] + bs0[g];
      float iv = sigf(gv[0]), fv = sigf(gv[1]), gg = tanhf_(gv[2]), ov = sigf(gv[3]);
      c0 = fv * c0 + iv * gg;
      float hv = ov * tanhf_(c0);
      __hip_atomic_store(HI0 + wro + (size_t)(b0 + um) * Hh + j0 + uj, pack_hl(hv),
                         __ATOMIC_RELAXED, __HIP_MEMORY_SCOPE_SYSTEM);
    }
    if (it >= 1) {
      float gv[4];
      #pragma unroll
      for (int g = 0; g < 4; ++g)
        gv[g] = p1[0][g][uj][um] + p1[1][g][uj][um] + p1[2][g][uj][um] + p1[3][g][uj][um] + bs1[g];
      float iv = sigf(gv[0]), fv = sigf(gv[1]), gg = tanhf_(gv[2]), ov = sigf(gv[3]);
      c1 = fv * c1 + iv * gg;
      float hv = ov * tanhf_(c1);
      __hip_atomic_store(HI1 + wro + (size_t)(b0 + um) * Hh + j0 + uj, pack_hl(hv),
                         __ATOMIC_RELAXED, __HIP_MEMORY_SCOPE_SYSTEM);
      if (it == Tt)
        __hip_atomic_store(HF + (size_t)(b0 + um) * Hh + j0 + uj, hv,
                           __ATOMIC_RELAXED, __HIP_MEMORY_SCOPE_SYSTEM);
    }

    group_barrier(FLG, it, gb, hs, lane, w4);
  }

  // ---- epilogue (in-group): block (gb, hs<16) -> out[gb*16 + hs], fp32 exact ----
  if (hs < 16 && tid < 64) {
    const int b = (gb << 4) + hs;
    float s = 0.f;
    #pragma unroll
    for (int i = 0; i < 8; ++i) {
      int j = i * 64 + tid;
      float hv = __hip_atomic_load(HF + (size_t)b * Hh + j, __ATOMIC_RELAXED,
                                   __HIP_MEMORY_SCOPE_SYSTEM);
      s += hv * linw[j];
    }
    #pragma unroll
    for (int off = 32; off >= 1; off >>= 1) s += __shfl_down(s, off, 64);
    if (tid == 0) out[b] = s + linb[0];
  }
}

extern "C" void kernel_launch(void* const* d_in, const int* in_sizes, int n_in,
                              void* d_out, int out_size, void* d_ws, size_t ws_size,
                              hipStream_t stream)
{
  const float* x    = (const float*)d_in[0];
  const float* wih0 = (const float*)d_in[1];
  const float* whh0 = (const float*)d_in[2];
  const float* bih0 = (const float*)d_in[3];
  const float* bhh0 = (const float*)d_in[4];
  const float* wih1 = (const float*)d_in[5];
  const float* whh1 = (const float*)d_in[6];
  const float* bih1 = (const float*)d_in[7];
  const float* bhh1 = (const float*)d_in[8];
  const float* linw = (const float*)d_in[9];
  const float* linb = (const float*)d_in[10];
  float* outp = (float*)d_out;
  unsigned char* ws = (unsigned char*)d_ws;

  prep<<<256, 256, 0, stream>>>(wih0, whh0, bih0, bhh0, wih1, whh1, bih1, bhh1, ws);

  lstm_main<<<256, 256, 0, stream>>>(
      (const __hip_bfloat16*)(ws + OFF_W0), (const __hip_bfloat16*)(ws + OFF_W1),
      (const float*)(ws + OFF_B0), (const float*)(ws + OFF_B1),
      (unsigned*)(ws + OFF_HI0), (unsigned*)(ws + OFF_HI1),
      (float*)(ws + OFF_HF), (unsigned*)(ws + OFF_FLG),
      x, linw, linb, outp);
}

// Round 6
// 2833.897 us; speedup vs baseline: 2.5728x; 1.5892x over previous
//
#include <hip/hip_runtime.h>
#include <hip/hip_bf16.h>

typedef __bf16 bf16x8 __attribute__((ext_vector_type(8)));
typedef float f32x4 __attribute__((ext_vector_type(4)));
typedef unsigned uint4v __attribute__((ext_vector_type(4)));
typedef unsigned long long u64;

constexpr int Bb = 128, Tt = 512, Ff = 64, Hh = 512, Gg = 2048;
constexpr int K0 = Hh + Ff;   // 576  = [h | x]
constexpr int K1 = Hh + Hh;   // 1024 = [h1 | h0]
constexpr int NITER = Tt + 1; // 513

// ws offsets (16B-aligned). h planes store PACKED u32 = bf16_hi | bf16_lo<<16
// (value = hi + lo, ~17 mantissa bits; exchanged via system-scope (IF$) ops).
constexpr size_t OFF_W0  = 0;                                   // bf16 [2048][576]  [w_hh_0 | w_ih_0]
constexpr size_t OFF_W1  = OFF_W0 + (size_t)Gg * K0 * 2;        // bf16 [2048][1024] [w_hh_1 | w_ih_1]
constexpr size_t OFF_B0  = OFF_W1 + (size_t)Gg * K1 * 2;        // f32 [2048]
constexpr size_t OFF_B1  = OFF_B0 + (size_t)Gg * 4;
constexpr size_t OFF_HI0 = OFF_B1 + (size_t)Gg * 4;             // u32 [2][128][512] (dbuf parity)
constexpr size_t OFF_HI1 = OFF_HI0 + (size_t)2 * Bb * Hh * 4;   // u32 [2][128][512]
constexpr size_t OFF_HF  = OFF_HI1 + (size_t)2 * Bb * Hh * 4;   // f32 [128][512] final h1
constexpr size_t OFF_FLG = OFF_HF + (size_t)Bb * Hh * 4;        // u32 [513][8][32] flag-per-WG barrier
// total ~8.9 MiB

__global__ void prep(const float* __restrict__ wih0, const float* __restrict__ whh0,
                     const float* __restrict__ bih0, const float* __restrict__ bhh0,
                     const float* __restrict__ wih1, const float* __restrict__ whh1,
                     const float* __restrict__ bih1, const float* __restrict__ bhh1,
                     unsigned char* __restrict__ ws)
{
  __hip_bfloat16* W0 = reinterpret_cast<__hip_bfloat16*>(ws + OFF_W0);
  __hip_bfloat16* W1 = reinterpret_cast<__hip_bfloat16*>(ws + OFF_W1);
  float* B0 = reinterpret_cast<float*>(ws + OFF_B0);
  float* B1 = reinterpret_cast<float*>(ws + OFF_B1);
  unsigned* HI0 = reinterpret_cast<unsigned*>(ws + OFF_HI0);
  unsigned* HI1 = reinterpret_cast<unsigned*>(ws + OFF_HI1);
  unsigned* FLG = reinterpret_cast<unsigned*>(ws + OFF_FLG);

  const size_t tid = (size_t)blockIdx.x * blockDim.x + threadIdx.x;
  const size_t stp = (size_t)gridDim.x * blockDim.x;

  for (size_t i = tid; i < (size_t)Gg * K0; i += stp) {
    int g = (int)(i / K0), k = (int)(i % K0);
    float v = (k < Hh) ? whh0[(size_t)g * Hh + k] : wih0[(size_t)g * Ff + (k - Hh)];
    W0[i] = __float2bfloat16(v);
  }
  for (size_t i = tid; i < (size_t)Gg * K1; i += stp) {
    int g = (int)(i / K1), k = (int)(i % K1);
    float v = (k < Hh) ? whh1[(size_t)g * Hh + k] : wih1[(size_t)g * Hh + (k - Hh)];
    W1[i] = __float2bfloat16(v);
  }
  for (size_t i = tid; i < (size_t)Gg; i += stp) {
    B0[i] = bih0[i] + bhh0[i];
    B1[i] = bih1[i] + bhh1[i];
  }
  // zero h planes (both parities; packed 0 == (0,0)) and ALL barrier flags
  for (size_t i = tid; i < (size_t)2 * Bb * Hh; i += stp) { HI0[i] = 0u; HI1[i] = 0u; }
  for (size_t i = tid; i < (size_t)NITER * 256; i += stp) FLG[i] = 0u;
}

__device__ __forceinline__ float sigf(float x)   { return 1.f / (1.f + __expf(-x)); }
__device__ __forceinline__ float tanhf_(float x) { return 1.f - 2.f / (1.f + __expf(2.f * x)); }

// pack value as bf16 hi|lo<<16 (RNE both)
__device__ __forceinline__ unsigned pack_hl(float v) {
  __bf16 hb = (__bf16)v;
  __bf16 lb = (__bf16)(v - (float)hb);
  return (unsigned)__builtin_bit_cast(unsigned short, hb)
       | ((unsigned)__builtin_bit_cast(unsigned short, lb) << 16);
}

// Read 8 packed u32 (k..k+7) for row fr from a swizzled LDS slab; unpack to
// hi/lo bf16x8. Swizzle col ^= (row&7)<<2 (u32 units, 16B granularity) puts the
// two b128 quads of the 64 lanes at the 8-cycle LDS floor (no excess conflicts).
__device__ __forceinline__ void lds_frag(const unsigned* sh, int fr, int cb,
                                         bf16x8& hi, bf16x8& lo) {
  const int sw = (fr & 7) << 2;
  const unsigned* row = sh + fr * Hh;
  uint4v qa = *reinterpret_cast<const uint4v*>(row + (cb ^ sw));
  uint4v qb = *reinterpret_cast<const uint4v*>(row + ((cb + 4) ^ sw));
  uint4v hw = { __builtin_amdgcn_perm(qa[1], qa[0], 0x05040100u),
                __builtin_amdgcn_perm(qa[3], qa[2], 0x05040100u),
                __builtin_amdgcn_perm(qb[1], qb[0], 0x05040100u),
                __builtin_amdgcn_perm(qb[3], qb[2], 0x05040100u) };
  uint4v lw = { __builtin_amdgcn_perm(qa[1], qa[0], 0x07060302u),
                __builtin_amdgcn_perm(qa[3], qa[2], 0x07060302u),
                __builtin_amdgcn_perm(qb[1], qb[0], 0x07060302u),
                __builtin_amdgcn_perm(qb[3], qb[2], 0x07060302u) };
  hi = __builtin_bit_cast(bf16x8, hw);
  lo = __builtin_bit_cast(bf16x8, lw);
}

// Contention-free group barrier: each WG stores 1 to its OWN flag slot after a
// vmcnt(0) drain (h-stores reached the IF$ coherence point first); wave 0's 32
// lanes poll the group's 32 slots in parallel. No RMW, no cache maintenance.
__device__ __forceinline__ void group_barrier(unsigned* FLG, int it, int gb, int hs,
                                              int lane, int w4) {
  asm volatile("s_waitcnt vmcnt(0)" ::: "memory");
  __syncthreads();
  unsigned* base = FLG + (size_t)it * 256 + gb * 32;
  if (threadIdx.x == 0)
    __hip_atomic_store(base + hs, 1u, __ATOMIC_RELAXED, __HIP_MEMORY_SCOPE_SYSTEM);
  if (w4 == 0 && lane < 32) {
    while (__hip_atomic_load(base + lane, __ATOMIC_RELAXED, __HIP_MEMORY_SCOPE_SYSTEM) == 0u) {}
  }
  asm volatile("" ::: "memory");
  __syncthreads();
}

// 256 WGs x 256 threads, 1 WG/CU. WG = (batch-group gb: 16 rows) x (hidden
// slice hs: 16 units); 4 waves K-split. Per iter: cooperatively stream the
// group's h0/h1 slabs (32 KB each) into LDS with coalesced u64 system-loads
// (one 2KB row per instruction), then build all MFMA fragments from LDS.
__global__ __launch_bounds__(256, 1)
void lstm_main(const __hip_bfloat16* __restrict__ W0, const __hip_bfloat16* __restrict__ W1,
               const float* __restrict__ B0, const float* __restrict__ B1,
               unsigned* __restrict__ HI0, unsigned* __restrict__ HI1,
               float* __restrict__ HF, unsigned* __restrict__ FLG,
               const float* __restrict__ xg,
               const float* __restrict__ linw, const float* __restrict__ linb,
               float* __restrict__ out)
{
  const int tid  = threadIdx.x;
  const int lane = tid & 63;
  const int w4   = tid >> 6;          // wave id 0..3 (K-split)
  const int gb   = blockIdx.x & 7;    // batch group
  const int hs   = blockIdx.x >> 3;   // hidden slice 0..31
  const int b0   = gb << 4;
  const int j0   = hs << 4;
  const int fr   = lane & 15;         // frag row (A batch-row / B gate-row)
  const int fk   = (lane >> 4) << 3;  // frag k offset within 32-k slice

  // LDS: two swizzled h slabs (32 KB each) + cross-wave partial sums (~10 KB)
  __shared__ unsigned sh0[16 * Hh];
  __shared__ unsigned sh1[16 * Hh];
  __shared__ float p0[4][4][16][20];
  __shared__ float p1[4][4][16][20];

  // layer-0 K split: 18 slices of 32 over 4 waves = {5,5,4,4}
  const int ks0 = (w4 < 2) ? w4 * 5 : 10 + (w4 - 2) * 4;
  const int kc0 = (w4 < 2) ? 5 : 4;

  // --- register-resident weight fragments (single bf16; pinned) ---
  bf16x8 wf0[4][5], wf1[4][8];
  #pragma unroll
  for (int g = 0; g < 4; ++g) {
    const size_t rw0 = (size_t)(g * Hh + j0 + fr) * K0;
    const size_t rw1 = (size_t)(g * Hh + j0 + fr) * K1;
    #pragma unroll
    for (int s = 0; s < 5; ++s) {
      int ks = ks0 + ((s < kc0) ? s : 0);   // clamp: unused slot replicates
      wf0[g][s] = *reinterpret_cast<const bf16x8*>(W0 + rw0 + ks * 32 + fk);
    }
    #pragma unroll
    for (int s = 0; s < 8; ++s)
      wf1[g][s] = *reinterpret_cast<const bf16x8*>(W1 + rw1 + (w4 * 8 + s) * 32 + fk);
  }
  #pragma unroll
  for (int g = 0; g < 4; ++g) {
    #pragma unroll
    for (int s = 0; s < 5; ++s) asm volatile("" : "+v"(wf0[g][s]));
    #pragma unroll
    for (int s = 0; s < 8; ++s) asm volatile("" : "+v"(wf1[g][s]));
  }

  // update-phase mapping: thread <-> (m = batch row-in-group, j = unit-in-slice)
  const int um = tid >> 4, uj = tid & 15;
  float bs0[4], bs1[4];
  #pragma unroll
  for (int g = 0; g < 4; ++g) {
    bs0[g] = B0[g * Hh + j0 + uj];
    bs1[g] = B1[g * Hh + j0 + uj];
  }
  float c0 = 0.f, c1 = 0.f;   // cell state fp32 in registers for the whole sequence

  // iteration it: layer0 computes t=it (it<512); layer1 computes t'=it-1 (it>=1)
  for (int it = 0; it <= Tt; ++it) {
    const int p = it & 1;
    const size_t rdo = (size_t)p * (Bb * Hh), wro = (size_t)(p ^ 1) * (Bb * Hh);

    // ---- A: issue slab loads (coalesced u64, IF$-coherent; 1 row / instr) ----
    u64 ld0[16], ld1[16];
    #pragma unroll
    for (int k = 0; k < 16; ++k)
      ld0[k] = __hip_atomic_load(
          reinterpret_cast<const u64*>(HI0 + rdo + (size_t)(b0 + k) * Hh) + tid,
          __ATOMIC_RELAXED, __HIP_MEMORY_SCOPE_SYSTEM);
    #pragma unroll
    for (int k = 0; k < 16; ++k)
      ld1[k] = __hip_atomic_load(
          reinterpret_cast<const u64*>(HI1 + rdo + (size_t)(b0 + k) * Hh) + tid,
          __ATOMIC_RELAXED, __HIP_MEMORY_SCOPE_SYSTEM);

    // ---- C: write slabs to LDS (XOR-swizzled), then sync ----
    #pragma unroll
    for (int k = 0; k < 16; ++k) {
      const int c = (tid * 2) ^ ((k & 7) << 2);
      *reinterpret_cast<u64*>(sh0 + k * Hh + c) = ld0[k];
      *reinterpret_cast<u64*>(sh1 + k * Hh + c) = ld1[k];
    }
    __syncthreads();

    // ---- D: layer 0: gates(t=it) = W0 * [h0 | x_t]  (A = hi+lo -> 2 MFMAs/slice) ----
    if (it < Tt) {
      bf16x8 ah[5], al[5];
      #pragma unroll
      for (int s = 0; s < 5; ++s) {
        const int k0 = (ks0 + ((s < kc0) ? s : 0)) * 32;
        if (k0 < Hh) {                       // h slices from LDS slab
          lds_frag(sh0, fr, k0 + fk, ah[s], al[s]);
        } else {                             // x part: split fp32 -> hi/lo in-register
          const float* xs = xg + ((size_t)(b0 + fr) * Tt + it) * Ff + (k0 - Hh) + fk;
          f32x4 v0 = *reinterpret_cast<const f32x4*>(xs);
          f32x4 v1 = *reinterpret_cast<const f32x4*>(xs + 4);
          bf16x8 hh, ll;
          #pragma unroll
          for (int j = 0; j < 4; ++j) {
            float v = v0[j];  __bf16 hb = (__bf16)v;
            hh[j] = hb;  ll[j] = (__bf16)(v - (float)hb);
            v = v1[j];  hb = (__bf16)v;
            hh[j + 4] = hb;  ll[j + 4] = (__bf16)(v - (float)hb);
          }
          ah[s] = hh;  al[s] = ll;
        }
      }
      f32x4 acc[4] = {};
      #pragma unroll
      for (int s = 0; s < 5; ++s) {
        if (s < kc0) {                       // wave-uniform
          #pragma unroll
          for (int g = 0; g < 4; ++g) {
            acc[g] = __builtin_amdgcn_mfma_f32_16x16x32_bf16(ah[s], wf0[g][s], acc[g], 0, 0, 0);
            acc[g] = __builtin_amdgcn_mfma_f32_16x16x32_bf16(al[s], wf0[g][s], acc[g], 0, 0, 0);
          }
        }
      }
      #pragma unroll
      for (int g = 0; g < 4; ++g)   // C/D: col(j)=lane&15, row(m)=4*(lane>>4)+r
        *reinterpret_cast<f32x4*>(&p0[w4][g][fr][(lane >> 4) << 2]) = acc[g];
    }

    // ---- D: layer 1: gates(t'=it-1) = W1 * [h1 | h0_new], all from LDS ----
    if (it >= 1) {
      f32x4 acc[4] = {};
      #pragma unroll
      for (int s = 0; s < 8; ++s) {
        const int k0 = (w4 * 8 + s) * 32;
        bf16x8 ah, al;
        if (k0 < Hh) lds_frag(sh1, fr, k0 + fk, ah, al);
        else         lds_frag(sh0, fr, (k0 - Hh) + fk, ah, al);
        #pragma unroll
        for (int g = 0; g < 4; ++g) {
          acc[g] = __builtin_amdgcn_mfma_f32_16x16x32_bf16(ah, wf1[g][s], acc[g], 0, 0, 0);
          acc[g] = __builtin_amdgcn_mfma_f32_16x16x32_bf16(al, wf1[g][s], acc[g], 0, 0, 0);
        }
      }
      #pragma unroll
      for (int g = 0; g < 4; ++g)
        *reinterpret_cast<f32x4*>(&p1[w4][g][fr][(lane >> 4) << 2]) = acc[g];
    }
    __syncthreads();

    // ---- E: cross-wave reduce + gates + state update + h publish (packed, IF$) ----
    if (it < Tt) {
      float gv[4];
      #pragma unroll
      for (int g = 0; g < 4; ++g)
        gv[g] = p0[0][g][uj][um] + p0[1][g][uj][um] + p0[2][g][uj][um] + p0[3][g][uj][um] + bs0[g];
      float iv = sigf(gv[0]), fv = sigf(gv[1]), gg = tanhf_(gv[2]), ov = sigf(gv[3]);
      c0 = fv * c0 + iv * gg;
      float hv = ov * tanhf_(c0);
      __hip_atomic_store(HI0 + wro + (size_t)(b0 + um) * Hh + j0 + uj, pack_hl(hv),
                         __ATOMIC_RELAXED, __HIP_MEMORY_SCOPE_SYSTEM);
    }
    if (it >= 1) {
      float gv[4];
      #pragma unroll
      for (int g = 0; g < 4; ++g)
        gv[g] = p1[0][g][uj][um] + p1[1][g][uj][um] + p1[2][g][uj][um] + p1[3][g][uj][um] + bs1[g];
      float iv = sigf(gv[0]), fv = sigf(gv[1]), gg = tanhf_(gv[2]), ov = sigf(gv[3]);
      c1 = fv * c1 + iv * gg;
      float hv = ov * tanhf_(c1);
      __hip_atomic_store(HI1 + wro + (size_t)(b0 + um) * Hh + j0 + uj, pack_hl(hv),
                         __ATOMIC_RELAXED, __HIP_MEMORY_SCOPE_SYSTEM);
      if (it == Tt)
        __hip_atomic_store(HF + (size_t)(b0 + um) * Hh + j0 + uj, hv,
                           __ATOMIC_RELAXED, __HIP_MEMORY_SCOPE_SYSTEM);
    }

    // ---- F: group barrier (drain + flag + parallel poll) ----
    group_barrier(FLG, it, gb, hs, lane, w4);
  }

  // ---- epilogue (in-group): block (gb, hs<16) -> out[gb*16 + hs], fp32 exact ----
  if (hs < 16 && tid < 64) {
    const int b = (gb << 4) + hs;
    float s = 0.f;
    #pragma unroll
    for (int i = 0; i < 8; ++i) {
      int j = i * 64 + tid;
      float hv = __hip_atomic_load(HF + (size_t)b * Hh + j, __ATOMIC_RELAXED,
                                   __HIP_MEMORY_SCOPE_SYSTEM);
      s += hv * linw[j];
    }
    #pragma unroll
    for (int off = 32; off >= 1; off >>= 1) s += __shfl_down(s, off, 64);
    if (tid == 0) out[b] = s + linb[0];
  }
}

extern "C" void kernel_launch(void* const* d_in, const int* in_sizes, int n_in,
                              void* d_out, int out_size, void* d_ws, size_t ws_size,
                              hipStream_t stream)
{
  const float* x    = (const float*)d_in[0];
  const float* wih0 = (const float*)d_in[1];
  const float* whh0 = (const float*)d_in[2];
  const float* bih0 = (const float*)d_in[3];
  const float* bhh0 = (const float*)d_in[4];
  const float* wih1 = (const float*)d_in[5];
  const float* whh1 = (const float*)d_in[6];
  const float* bih1 = (const float*)d_in[7];
  const float* bhh1 = (const float*)d_in[8];
  const float* linw = (const float*)d_in[9];
  const float* linb = (const float*)d_in[10];
  float* outp = (float*)d_out;
  unsigned char* ws = (unsigned char*)d_ws;

  prep<<<256, 256, 0, stream>>>(wih0, whh0, bih0, bhh0, wih1, whh1, bih1, bhh1, ws);

  lstm_main<<<256, 256, 0, stream>>>(
      (const __hip_bfloat16*)(ws + OFF_W0), (const __hip_bfloat16*)(ws + OFF_W1),
      (const float*)(ws + OFF_B0), (const float*)(ws + OFF_B1),
      (unsigned*)(ws + OFF_HI0), (unsigned*)(ws + OFF_HI1),
      (float*)(ws + OFF_HF), (unsigned*)(ws + OFF_FLG),
      x, linw, linb, outp);
}